// Round 5
// baseline (5917.389 us; speedup 1.0000x reference)
//
#include <hip/hip_runtime.h>
#include <math.h>

#define B 128
#define N 1000
#define NP 1024
#define D 128
#define H 8
#define DK 16
#define STEPS 64
#define NEG_INF (-INFINITY)
#define OUT_NEG (-1.0e30f)   // finite stand-in for -inf in OUTPUT only

// ---------------- ws layout (floats) ----------------
// fixed_ctx : B*D
// lKt       : B*D*NP  (logitK transposed [b][d][n], n padded to 1024)
// wePg      : B*8*8*128  per (b,wave,h): normalized weighted-emb wave-partial
// first_emb : B*D
// prev_emb  : B*D
// visited   : B*NP ints

// ============================================================
// Precompute lKt only: lK = emb @ W_node[:,256:384], stored transposed.
// Same GEMM body as the round-2 kernel that passed (cc==2 path).
// ============================================================
__global__ __launch_bounds__(256)
void precompute_lkt(const float* __restrict__ emb, const float* __restrict__ Wn,
                    float* __restrict__ lKt) {
  const int rt = blockIdx.x;          // row tile (128 rows of flattened B*N)
  const int t  = threadIdx.x;
  const int tx = t & 15, ty = t >> 4; // 16 x 16
  __shared__ float4 wL[64 * 32];      // 32 KB

  float acc[8][8];
#pragma unroll
  for (int i = 0; i < 8; ++i)
#pragma unroll
    for (int j = 0; j < 8; ++j) acc[i][j] = 0.f;

  const float4* Wn4 = (const float4*)Wn;
  const float* ebase = emb + (size_t)(rt * 128 + ty * 8) * 128;

  for (int kk = 0; kk < 2; ++kk) {
    __syncthreads();
    for (int idx = t; idx < 64 * 32; idx += 256) {
      int dl = idx >> 5, c4 = idx & 31;
      wL[dl * 32 + c4] = Wn4[(size_t)(kk * 64 + dl) * 96 + 64 + c4];  // cols 256..383
    }
    __syncthreads();
    for (int dl = 0; dl < 64; dl += 4) {
      float4 e4[8];
#pragma unroll
      for (int i = 0; i < 8; ++i)
        e4[i] = *(const float4*)(ebase + (size_t)i * 128 + kk * 64 + dl);
#pragma unroll
      for (int dd = 0; dd < 4; ++dd) {
        float4 w0 = wL[(dl + dd) * 32 + tx * 2];
        float4 w1 = wL[(dl + dd) * 32 + tx * 2 + 1];
        float w_[8] = {w0.x, w0.y, w0.z, w0.w, w1.x, w1.y, w1.z, w1.w};
        float e_[8] = {
          dd == 0 ? e4[0].x : dd == 1 ? e4[0].y : dd == 2 ? e4[0].z : e4[0].w,
          dd == 0 ? e4[1].x : dd == 1 ? e4[1].y : dd == 2 ? e4[1].z : e4[1].w,
          dd == 0 ? e4[2].x : dd == 1 ? e4[2].y : dd == 2 ? e4[2].z : e4[2].w,
          dd == 0 ? e4[3].x : dd == 1 ? e4[3].y : dd == 2 ? e4[3].z : e4[3].w,
          dd == 0 ? e4[4].x : dd == 1 ? e4[4].y : dd == 2 ? e4[4].z : e4[4].w,
          dd == 0 ? e4[5].x : dd == 1 ? e4[5].y : dd == 2 ? e4[5].z : e4[5].w,
          dd == 0 ? e4[6].x : dd == 1 ? e4[6].y : dd == 2 ? e4[6].z : e4[6].w,
          dd == 0 ? e4[7].x : dd == 1 ? e4[7].y : dd == 2 ? e4[7].z : e4[7].w};
#pragma unroll
        for (int i = 0; i < 8; ++i)
#pragma unroll
          for (int j = 0; j < 8; ++j) acc[i][j] += e_[i] * w_[j];
      }
    }
  }

#pragma unroll
  for (int i = 0; i < 8; ++i) {
    int row = rt * 128 + ty * 8 + i;   // 0..127999
    int b = row / 1000;
    int n = row - b * 1000;
#pragma unroll
    for (int j = 0; j < 8; ++j)
      lKt[((size_t)b * D + tx * 8 + j) * NP + n] = acc[i][j];
  }
}

// ============================================================
// fixed_ctx[b] = mean_n(emb[b]) @ W_fixed   (verbatim round 2)
// ============================================================
__global__ __launch_bounds__(256)
void fixed_ctx_kernel(const float* __restrict__ emb, const float* __restrict__ Wf,
                      float* __restrict__ fixed_ctx) {
  const int b = blockIdx.x;
  const int t = threadIdx.x;
  const int d = t & 127, half = t >> 7;
  __shared__ float part[256];
  __shared__ float meanL[128];
  float s = 0.f;
  for (int n = half; n < N; n += 2) s += emb[((size_t)b * N + n) * D + d];
  part[t] = s;
  __syncthreads();
  if (t < 128) meanL[t] = (part[t] + part[t + 128]) * (1.0f / (float)N);
  __syncthreads();
  if (t < 128) {
    float a = 0.f;
    for (int k = 0; k < 128; ++k) a += meanL[k] * Wf[k * 128 + t];
    fixed_ctx[b * 128 + t] = a;
  }
}

// ============================================================
// glimpse_emb: one block per b (512 thr = 8 waves). Self-contained:
// q = fixed + ctx@Wstep; qk_h = (q_h @ Wk_h^T)/4 (back-projection so compat
// reads RAW emb); compat[8][1024] in LDS; full in-block softmax per head
// (wave h owns head h); weighted-emb accumulation; normalized per-wave
// partials to global wePg[b][wv][h][128]. No cross-block state.
// ============================================================
__global__ __launch_bounds__(512)
void glimpse_emb(const float* __restrict__ emb, const float* __restrict__ Wn,
                 const float* __restrict__ Wstep, const float* __restrict__ Wp,
                 const float* __restrict__ fixed_ctx,
                 const float* __restrict__ first_emb, const float* __restrict__ prev_emb,
                 const int* __restrict__ visited,
                 float* __restrict__ wePg, int step) {
  const int b = blockIdx.x;
  const int t = threadIdx.x;
  const int lane = t & 63, wv = t >> 6;
  const int r = (lane >> 4) & 3, c = lane & 15;

  __shared__ float ctxL[256];
  __shared__ float qL[128];
  __shared__ float qkL[8][128];
  __shared__ float cL[8][1024];     // 32 KB
  __shared__ float sH[8];

  // ---- stage step context ----
  if (t < 256) {
    float v;
    if (step == 0) v = Wp[t];
    else v = (t < 128) ? first_emb[b * D + t] : prev_emb[b * D + (t - 128)];
    ctxL[t] = v;
  }
  __syncthreads();

  // ---- q = fixed_ctx + ctx @ W_step ----
  if (t < 128) {
    float a = fixed_ctx[b * D + t];
    for (int i = 0; i < 256; ++i) a += ctxL[i] * Wstep[i * D + t];
    qL[t] = a;
  }
  __syncthreads();

  // ---- qk[h][d] = 0.25 * sum_k q[h*16+k] * Wk[d][h*16+k] ----
  {
    int d = t >> 2, h0 = (t & 3) * 2;
#pragma unroll
    for (int u = 0; u < 2; ++u) {
      int hh = h0 + u;
      float a = 0.f;
#pragma unroll
      for (int k = 0; k < 16; ++k) a += qL[hh * 16 + k] * Wn[(size_t)d * 384 + hh * 16 + k];
      qkL[hh][d] = a * 0.25f;   // 1/sqrt(dk)
    }
  }
  __syncthreads();

  const float4* emb4 = (const float4*)emb;

  // ---- compat: cL[h][n] = qk_h . emb[n] (masked) ----
  {
    float qkr[8][8];
#pragma unroll
    for (int h = 0; h < 8; ++h)
#pragma unroll
      for (int j = 0; j < 8; ++j) qkr[h][j] = qkL[h][c * 8 + j];

    for (int it = 0; it < 32; ++it) {
      int n = it * 32 + wv * 4 + r;          // 0..1023
      float4 e0 = make_float4(0.f, 0.f, 0.f, 0.f), e1 = e0;
      if (n < N) {
        e0 = emb4[((size_t)b * N + n) * 32 + c * 2];
        e1 = emb4[((size_t)b * N + n) * 32 + c * 2 + 1];
      }
      float s[8];
#pragma unroll
      for (int h = 0; h < 8; ++h) {
        s[h] = qkr[h][0] * e0.x + qkr[h][1] * e0.y + qkr[h][2] * e0.z + qkr[h][3] * e0.w
             + qkr[h][4] * e1.x + qkr[h][5] * e1.y + qkr[h][6] * e1.z + qkr[h][7] * e1.w;
      }
#pragma unroll
      for (int off = 1; off <= 8; off <<= 1)
#pragma unroll
        for (int h = 0; h < 8; ++h) s[h] += __shfl_xor(s[h], off);
      if (c == 0) {
        bool vis = (n >= N) || (visited[b * NP + n] != 0);
#pragma unroll
        for (int h = 0; h < 8; ++h) cL[h][n] = vis ? NEG_INF : s[h];
      }
    }
  }
  __syncthreads();

  // ---- full in-block softmax for head h = wv; cL becomes unnormalized p ----
  {
    int h = wv;
    float vals[16];
    float m = NEG_INF;
#pragma unroll
    for (int j = 0; j < 16; ++j) { vals[j] = cL[h][lane + j * 64]; m = fmaxf(m, vals[j]); }
#pragma unroll
    for (int off = 1; off <= 32; off <<= 1) m = fmaxf(m, __shfl_xor(m, off));
    float ssum = 0.f;
#pragma unroll
    for (int j = 0; j < 16; ++j) {
      float p = (vals[j] == NEG_INF) ? 0.f : expf(vals[j] - m);
      cL[h][lane + j * 64] = p;
      ssum += p;
    }
#pragma unroll
    for (int off = 1; off <= 32; off <<= 1) ssum += __shfl_xor(ssum, off);
    if (lane == 0) sH[h] = ssum;
  }
  __syncthreads();

  // ---- weighted emb: wa[h][j] = sum_n p[h][n] * emb[n][c*8+j] ----
  float wa[8][8];
#pragma unroll
  for (int h = 0; h < 8; ++h)
#pragma unroll
    for (int j = 0; j < 8; ++j) wa[h][j] = 0.f;

  for (int it = 0; it < 32; ++it) {
    int n = it * 32 + wv * 4 + r;
    if (n < N) {
      float4 e0 = emb4[((size_t)b * N + n) * 32 + c * 2];
      float4 e1 = emb4[((size_t)b * N + n) * 32 + c * 2 + 1];
#pragma unroll
      for (int h = 0; h < 8; ++h) {
        float p = cL[h][n];
        wa[h][0] += p * e0.x; wa[h][1] += p * e0.y;
        wa[h][2] += p * e0.z; wa[h][3] += p * e0.w;
        wa[h][4] += p * e1.x; wa[h][5] += p * e1.y;
        wa[h][6] += p * e1.z; wa[h][7] += p * e1.w;
      }
    }
  }
  // reduce over the 4 row-lanes (lane bits 4,5)
#pragma unroll
  for (int h = 0; h < 8; ++h)
#pragma unroll
    for (int j = 0; j < 8; ++j) {
      wa[h][j] += __shfl_xor(wa[h][j], 16);
      wa[h][j] += __shfl_xor(wa[h][j], 32);
    }
  // normalized per-wave partial to global
  if (lane < 16) {
#pragma unroll
    for (int h = 0; h < 8; ++h) {
      float inv = 1.0f / sH[h];
      float* dst = wePg + ((size_t)(b * 8 + wv) * 8 + h) * 128 + lane * 8;
      *(float4*)dst       = make_float4(wa[h][0] * inv, wa[h][1] * inv, wa[h][2] * inv, wa[h][3] * inv);
      *(float4*)(dst + 4) = make_float4(wa[h][4] * inv, wa[h][5] * inv, wa[h][6] * inv, wa[h][7] * inv);
    }
  }
}

// ============================================================
// K2 (round-2 logits kernel + heads prologue): per b: sum wave partials ->
// weN -> heads (proj through Wv) -> glimpse -> logits via lKt -> tanh clip,
// mask, log_softmax, argmax, state update, outputs. All state in ONE kernel.
// ============================================================
__global__ __launch_bounds__(256)
void logits_kernel(const float* __restrict__ lKt, const float* __restrict__ wePg,
                   const float* __restrict__ Wn, const float* __restrict__ W_out,
                   const float* __restrict__ emb,
                   int* __restrict__ visited, float* __restrict__ first_emb,
                   float* __restrict__ prev_emb, float* __restrict__ out, int step) {
  const int b = blockIdx.x;
  const int t = threadIdx.x;
  const int lane = t & 63, wid = t >> 6;
  __shared__ float weN[8][128];
  __shared__ float headsL[128];
  __shared__ float gl[128];
  __shared__ float redV[4];
  __shared__ int   redI[4];
  __shared__ float mS;
  __shared__ int   selS;

  // sum the 8 wave partials -> weN
  for (int idx = t; idx < 1024; idx += 256) {
    float a = 0.f;
    for (int w = 0; w < 8; ++w) a += wePg[(size_t)(b * 8 + w) * 1024 + idx];
    weN[idx >> 7][idx & 127] = a;
  }
  __syncthreads();
  // heads[h*16+k] = sum_d weN[h][d] * Wv[d][h*16+k]
  if (t < 128) {
    int h = t >> 4, k = t & 15;
    float a = 0.f;
    for (int d = 0; d < 128; ++d) a += weN[h][d] * Wn[(size_t)d * 384 + 128 + h * 16 + k];
    headsL[t] = a;
  }
  __syncthreads();
  // glimpse = heads @ W_out
  if (t < 128) {
    float a = 0.f;
    for (int k = 0; k < 128; ++k) a += headsL[k] * W_out[k * 128 + t];
    gl[t] = a;
  }
  __syncthreads();

  // logits: thread t owns n = 4t..4t+3
  float acc[4] = {0.f, 0.f, 0.f, 0.f};
  const float4* lk4 = (const float4*)(lKt + (size_t)b * D * NP);
  for (int d = 0; d < 128; ++d) {
    float g = gl[d];
    float4 v = lk4[d * (NP / 4) + t];
    acc[0] += g * v.x; acc[1] += g * v.y; acc[2] += g * v.z; acc[3] += g * v.w;
  }
  const float sqrtD = 11.313708498984761f;  // sqrt(128)
  float lv[4];
  int ok[4];
#pragma unroll
  for (int j = 0; j < 4; ++j) {
    int n = t * 4 + j;
    int valid = (n < N) && (visited[b * NP + n] == 0);
    float l = 10.f * tanhf(acc[j] / sqrtD);
    lv[j] = valid ? l : NEG_INF;
    ok[j] = valid;
  }

  // argmax (first-index tie-break) == max for softmax
  float bv = lv[0];
  int bi = t * 4;
#pragma unroll
  for (int j = 1; j < 4; ++j)
    if (lv[j] > bv) { bv = lv[j]; bi = t * 4 + j; }
#pragma unroll
  for (int off = 32; off >= 1; off >>= 1) {
    float ov = __shfl_xor(bv, off);
    int oi = __shfl_xor(bi, off);
    if (ov > bv || (ov == bv && oi < bi)) { bv = ov; bi = oi; }
  }
  if (lane == 0) { redV[wid] = bv; redI[wid] = bi; }
  __syncthreads();
  if (t == 0) {
    float mv = redV[0]; int mi = redI[0];
    for (int w = 1; w < 4; ++w)
      if (redV[w] > mv || (redV[w] == mv && redI[w] < mi)) { mv = redV[w]; mi = redI[w]; }
    mS = mv; selS = mi;
  }
  __syncthreads();
  const float m = mS;

  float se = 0.f;
#pragma unroll
  for (int j = 0; j < 4; ++j) if (ok[j]) se += expf(lv[j] - m);
#pragma unroll
  for (int off = 32; off >= 1; off >>= 1) se += __shfl_xor(se, off);
  __syncthreads();                  // reads of redV (argmax) complete
  if (lane == 0) redV[wid] = se;
  __syncthreads();
  se = redV[0] + redV[1] + redV[2] + redV[3];
  const float lse = m + logf(se);

  // write logp row (finite stand-in at masked entries)
  if (t < 250) {
    float4 o;
    o.x = ok[0] ? (lv[0] - lse) : OUT_NEG;
    o.y = ok[1] ? (lv[1] - lse) : OUT_NEG;
    o.z = ok[2] ? (lv[2] - lse) : OUT_NEG;
    o.w = ok[3] ? (lv[3] - lse) : OUT_NEG;
    ((float4*)(out + ((size_t)b * STEPS + step) * N))[t] = o;
  }

  const int sel = selS;
  if (t == 0) {
    out[(size_t)B * STEPS * N + b * STEPS + step] = (float)sel;
    visited[b * NP + sel] = 1;
  }
  if (t < 128) {
    float e = emb[((size_t)b * N + sel) * D + t];
    prev_emb[b * D + t] = e;
    if (step == 0) first_emb[b * D + t] = e;
  }
}

// ============================================================
extern "C" void kernel_launch(void* const* d_in, const int* in_sizes, int n_in,
                              void* d_out, int out_size, void* d_ws, size_t ws_size,
                              hipStream_t stream) {
  (void)in_sizes; (void)n_in; (void)out_size; (void)ws_size;
  const float* emb     = (const float*)d_in[0];
  const float* W_node  = (const float*)d_in[1];
  const float* W_fixed = (const float*)d_in[2];
  const float* W_step  = (const float*)d_in[3];
  const float* W_out   = (const float*)d_in[4];
  const float* Wp      = (const float*)d_in[5];
  float* out = (float*)d_out;
  float* ws  = (float*)d_ws;

  float* fixed_ctx = ws;
  float* lKt       = fixed_ctx + (size_t)B * D;
  float* wePg      = lKt + (size_t)B * D * NP;
  float* first_emb = wePg + (size_t)B * 8 * 8 * 128;
  float* prev_emb  = first_emb + (size_t)B * D;
  int*   visited   = (int*)(prev_emb + (size_t)B * D);

  hipMemsetAsync(visited, 0, (size_t)B * NP * sizeof(int), stream);
  precompute_lkt<<<1000, 256, 0, stream>>>(emb, W_node, lKt);
  fixed_ctx_kernel<<<B, 256, 0, stream>>>(emb, W_fixed, fixed_ctx);
  for (int s = 0; s < STEPS; ++s) {
    glimpse_emb<<<B, 512, 0, stream>>>(emb, W_node, W_step, Wp, fixed_ctx,
                                       first_emb, prev_emb, visited, wePg, s);
    logits_kernel<<<B, 256, 0, stream>>>(lKt, wePg, W_node, W_out, emb, visited,
                                         first_emb, prev_emb, out, s);
  }
}